// Round 6
// baseline (626.668 us; speedup 1.0000x reference)
//
#include <hip/hip_runtime.h>
#include <hip/hip_bf16.h>

// HGNN: out = BN(ReLU( segmax( BN(ReLU(concat(lf[li], dcoor) @ W1 + b1)) ) @ W2 + b2))
//   gemm0: G = lf @ W1[:300] + b1 -> bf16 [N_last][320]; reads fp32 lf DIRECTLY
//          (cvt fused into LDS staging).
//   edge_pass: y = ReLU(G[li] + delta . Wc); counting-sorted edges, block owns
//          SEGB contiguous cur-segments -> plain float2 stores of running max
//          (m = max sgn*y), NO atomics, NO zbuf memset (empty = segEnd gap).
//   gemm1: A = agg = |a1|*m + c1 (BN1 affine, empty rows -> 0) fused into LDS
//          staging from zbuf; out_pre = ReLU(A @ W2 + b2) + stats partials.
//   gemm v2 (latency fix): B fragments read DIRECT from L2-resident WT (no Bs
//          LDS -> 20KB/block, 4 blocks/CU via __launch_bounds__(256,4));
//          A staging = load-all-8-float4 THEN cvt+store (max loads in flight);
//          grid (2, Mtiles) so both N-tiles of an A-panel are L2-paired.
// ac layout: a[c] at ac[c] (c<320, pads 0), offset at ac[320+c] (pads 0).

#define NPART 64
#define SB 256      // scan block
#define SEGB 32     // cur segments owned per edge_pass block (2 streams x 16)
#define CHS 256     // staged edges per stream chunk
#define UNR 8       // edge_pass load batch depth

typedef __bf16 bf16_t;
typedef __bf16 bf16x8 __attribute__((ext_vector_type(8)));
typedef float f32x4 __attribute__((ext_vector_type(4)));

// ---------- counting sort: hist -> scan -> scatter ----------
__global__ void hist_k(const int* __restrict__ ci, int E, int* __restrict__ hist)
{
    const int e = blockIdx.x * 256 + threadIdx.x;
    if (e < E) atomicAdd(&hist[ci[e]], 1);
}

__global__ void scan_reduce(const int* __restrict__ hist, int nseg, int* __restrict__ bsum)
{
    __shared__ int s[SB];
    const int tid = threadIdx.x;
    const int i = blockIdx.x * SB + tid;
    s[tid] = (i < nseg) ? hist[i] : 0;
    __syncthreads();
    for (int o = SB / 2; o > 0; o >>= 1) {
        if (tid < o) s[tid] += s[tid + o];
        __syncthreads();
    }
    if (tid == 0) bsum[blockIdx.x] = s[0];
}

__global__ void scan_top(int* __restrict__ bsum, int nb)
{
    __shared__ int s[SB];
    const int tid = threadIdx.x;
    const int v = (tid < nb) ? bsum[tid] : 0;
    s[tid] = v;
    __syncthreads();
    for (int o = 1; o < SB; o <<= 1) {
        int x = 0;
        if (tid >= o) x = s[tid - o];
        __syncthreads();
        s[tid] += x;
        __syncthreads();
    }
    if (tid < nb) bsum[tid] = s[tid] - v;   // exclusive
}

__global__ void scan_final(const int* __restrict__ hist, int nseg,
                           const int* __restrict__ bsum, int* __restrict__ cnt)
{
    __shared__ int s[SB];
    const int tid = threadIdx.x;
    const int i = blockIdx.x * SB + tid;
    const int v = (i < nseg) ? hist[i] : 0;
    s[tid] = v;
    __syncthreads();
    for (int o = 1; o < SB; o <<= 1) {
        int x = 0;
        if (tid >= o) x = s[tid - o];
        __syncthreads();
        s[tid] += x;
        __syncthreads();
    }
    if (i < nseg) cnt[i] = s[tid] - v + bsum[blockIdx.x];
}

__global__ void scatter_k(const int* __restrict__ ci, const int* __restrict__ li,
                          int E, int* __restrict__ cnt, int2* __restrict__ sorted)
{
    const int e = blockIdx.x * 256 + threadIdx.x;
    if (e >= E) return;
    const int c = ci[e];
    const int pos = atomicAdd(&cnt[c], 1);
    sorted[pos] = make_int2(li[e], c);
    // after this kernel: cnt[c] = END offset of segment c in sorted[]
}

// ---------- pack BOTH W (fp32 [300][300] row-major) -> WT bf16 [2][384][320] ----------
__global__ void pack_wt2(const float* __restrict__ W1, const float* __restrict__ W2,
                         bf16_t* __restrict__ WT)
{
    const int idx = blockIdx.x * 256 + threadIdx.x;
    if (idx >= 2 * 384 * 320) return;
    const int w = idx / (384 * 320);
    const int rem = idx - w * (384 * 320);
    const int n = rem / 320, k = rem % 320;
    const float* W = w ? W2 : W1;
    float v = (n < 300 && k < 300) ? W[k * 300 + n] : 0.f;
    WT[idx] = (bf16_t)v;
}

// ---------- MFMA bf16 GEMM with fused A-staging transform ----------
// MODE 0: A32 = lf fp32 [M][300]; stage cvt->bf16 (zero-pad cols>=300);
//         epilogue: +bias, bf16 [M][320] to outBF (pad cols zeroed).
// MODE 1: A32 = zbuf float [M][320] (seg running max m); stage
//         v = empty(r) ? 0 : |ac[c]|*m + ac[320+c]  (ac pads are 0);
//         epilogue: ReLU(+bias), fp32 [M][300] to outF, stats partials.
// B fragments read directly from WT (global; L2-resident, no LDS staging).
// grid = (2, Mtiles): m0 = blockIdx.y*128, n0 = blockIdx.x*160.
template<int MODE>
__launch_bounds__(256, 4)
__global__ void gemm_mfma(const float* __restrict__ A32, int M,
                          const int* __restrict__ segEnd,   // MODE 1
                          const float* __restrict__ ac,     // MODE 1 (640 floats)
                          const bf16_t* __restrict__ WT,
                          const float* __restrict__ bias,
                          bf16_t* __restrict__ outBF,
                          float* __restrict__ outF,
                          float* __restrict__ part)
{
    __shared__ bf16_t As[128][72];
    __shared__ float sSum[160], sSq[160];

    const int tid  = threadIdx.x;
    const int lane = tid & 63, wv = tid >> 6;
    const int wm = wv & 1, wn = wv >> 1;
    const int m0 = blockIdx.y * 128, n0 = blockIdx.x * 160;
    const int rl = lane & 15, quad = lane >> 4;

    if (MODE == 1 && tid < 160) { sSum[tid] = 0.f; sSq[tid] = 0.f; }

    // staging geometry: thread owns col-chunk kcT (8 cols) of rows {rT+0,32,64,96}
    const int kcT = (tid & 7) * 8;
    const int rT  = tid >> 3;
    int grow[4]; bool emp[4];
    #pragma unroll
    for (int i = 0; i < 4; ++i) {
        grow[i] = min(m0 + i * 32 + rT, M - 1);
        emp[i] = false;
        if (MODE == 1)
            emp[i] = segEnd[grow[i]] == (grow[i] ? segEnd[grow[i] - 1] : 0);
    }

    f32x4 acc[4][5];
    #pragma unroll
    for (int i = 0; i < 4; ++i)
        #pragma unroll
        for (int j = 0; j < 5; ++j)
            acc[i][j] = (f32x4){0.f, 0.f, 0.f, 0.f};

    for (int k0 = 0; k0 < 320; k0 += 64) {
        const int c0 = k0 + kcT;

        // ---- load pass: all 8 float4 (+ac) issued before any LDS write ----
        float4 la[4], lb[4];
        float4 aa, ab, ca, cb;
        if (MODE == 1) {
            aa = *reinterpret_cast<const float4*>(&ac[c0]);
            ab = *reinterpret_cast<const float4*>(&ac[c0 + 4]);
            ca = *reinterpret_cast<const float4*>(&ac[320 + c0]);
            cb = *reinterpret_cast<const float4*>(&ac[320 + c0 + 4]);
        }
        #pragma unroll
        for (int i = 0; i < 4; ++i) {
            la[i] = make_float4(0.f, 0.f, 0.f, 0.f);
            lb[i] = make_float4(0.f, 0.f, 0.f, 0.f);
            if (MODE == 0) {
                if (c0 + 8 <= 300) {
                    la[i] = *reinterpret_cast<const float4*>(&A32[(long)grow[i] * 300 + c0]);
                    lb[i] = *reinterpret_cast<const float4*>(&A32[(long)grow[i] * 300 + c0 + 4]);
                } else if (c0 < 300) {   // c0 == 296
                    la[i] = *reinterpret_cast<const float4*>(&A32[(long)grow[i] * 300 + c0]);
                }
            } else {
                la[i] = *reinterpret_cast<const float4*>(&A32[(long)grow[i] * 320 + c0]);
                lb[i] = *reinterpret_cast<const float4*>(&A32[(long)grow[i] * 320 + c0 + 4]);
            }
        }
        // ---- transform + LDS store ----
        #pragma unroll
        for (int i = 0; i < 4; ++i) {
            bf16x8 v;
            if (MODE == 0) {
                v = (bf16x8){(bf16_t)la[i].x, (bf16_t)la[i].y, (bf16_t)la[i].z, (bf16_t)la[i].w,
                             (bf16_t)lb[i].x, (bf16_t)lb[i].y, (bf16_t)lb[i].z, (bf16_t)lb[i].w};
            } else {
                const float t0 = emp[i] ? 0.f : fabsf(aa.x) * la[i].x + ca.x;
                const float t1 = emp[i] ? 0.f : fabsf(aa.y) * la[i].y + ca.y;
                const float t2 = emp[i] ? 0.f : fabsf(aa.z) * la[i].z + ca.z;
                const float t3 = emp[i] ? 0.f : fabsf(aa.w) * la[i].w + ca.w;
                const float t4 = emp[i] ? 0.f : fabsf(ab.x) * lb[i].x + cb.x;
                const float t5 = emp[i] ? 0.f : fabsf(ab.y) * lb[i].y + cb.y;
                const float t6 = emp[i] ? 0.f : fabsf(ab.z) * lb[i].z + cb.z;
                const float t7 = emp[i] ? 0.f : fabsf(ab.w) * lb[i].w + cb.w;
                v = (bf16x8){(bf16_t)t0, (bf16_t)t1, (bf16_t)t2, (bf16_t)t3,
                             (bf16_t)t4, (bf16_t)t5, (bf16_t)t6, (bf16_t)t7};
            }
            *reinterpret_cast<bf16x8*>(&As[i * 32 + rT][kcT]) = v;
        }
        __syncthreads();

        #pragma unroll
        for (int kk = 0; kk < 2; ++kk) {
            const int kb = kk * 32 + quad * 8;
            bf16x8 af[4], bfr[5];
            #pragma unroll
            for (int nj = 0; nj < 5; ++nj)
                bfr[nj] = *reinterpret_cast<const bf16x8*>(
                    &WT[(long)(n0 + wn * 80 + nj * 16 + rl) * 320 + k0 + kb]);
            #pragma unroll
            for (int mi = 0; mi < 4; ++mi)
                af[mi] = *reinterpret_cast<const bf16x8*>(&As[wm * 64 + mi * 16 + rl][kb]);
            #pragma unroll
            for (int mi = 0; mi < 4; ++mi)
                #pragma unroll
                for (int nj = 0; nj < 5; ++nj)
                    acc[mi][nj] = __builtin_amdgcn_mfma_f32_16x16x32_bf16(
                        af[mi], bfr[nj], acc[mi][nj], 0, 0, 0);
        }
        __syncthreads();
    }

    // epilogue: C/D layout col = lane&15, row = quad*4 + reg
    if (MODE == 0) {
        #pragma unroll
        for (int mi = 0; mi < 4; ++mi)
            #pragma unroll
            for (int nj = 0; nj < 5; ++nj)
                #pragma unroll
                for (int reg = 0; reg < 4; ++reg) {
                    const int r = m0 + wm * 64 + mi * 16 + quad * 4 + reg;
                    const int c = n0 + wn * 80 + nj * 16 + rl;   // < 320
                    if (r < M) {
                        const float v = (c < 300) ? (acc[mi][nj][reg] + bias[c]) : 0.f;
                        outBF[(long)r * 320 + c] = (bf16_t)v;
                    }
                }
    } else {
        float csum[5] = {}, csq[5] = {};
        #pragma unroll
        for (int mi = 0; mi < 4; ++mi)
            #pragma unroll
            for (int nj = 0; nj < 5; ++nj)
                #pragma unroll
                for (int reg = 0; reg < 4; ++reg) {
                    const int r = m0 + wm * 64 + mi * 16 + quad * 4 + reg;
                    const int c = n0 + wn * 80 + nj * 16 + rl;
                    if (r < M && c < 300) {
                        float v = fmaxf(acc[mi][nj][reg] + bias[c], 0.f);
                        outF[(long)r * 300 + c] = v;
                        csum[nj] += v; csq[nj] += v * v;
                    }
                }
        #pragma unroll
        for (int nj = 0; nj < 5; ++nj) {
            const int cl = wn * 80 + nj * 16 + rl;
            atomicAdd(&sSum[cl], csum[nj]);
            atomicAdd(&sSq[cl], csq[nj]);
        }
        __syncthreads();
        const int slot = (blockIdx.x + blockIdx.y * gridDim.x) & (NPART - 1);
        if (tid < 160 && (n0 + tid) < 300) {
            atomicAdd(&part[slot * 600 + n0 + tid], sSum[tid]);
            atomicAdd(&part[slot * 600 + 300 + n0 + tid], sSq[tid]);
        }
    }
}

// ---------- edge pass: block owns SEGB contiguous segments; plain float stores ----------
__launch_bounds__(320)
__global__ void edge_pass(const bf16_t* __restrict__ Gb,   // [N_last][320]
                          const float* __restrict__ last_coors,
                          const float* __restrict__ cur_coors,
                          const int2* __restrict__ sorted,  // (li, ci), sorted by ci
                          const int*  __restrict__ segEnd,  // end offsets per cur node
                          const float* __restrict__ Wc,     // rows 300..302 of W1, 3x300
                          const float* __restrict__ g1,
                          float* __restrict__ zbuf,         // [N_cur][320] raw max (m)
                          float* __restrict__ part1,
                          int N_cur)
{
    __shared__ int sRow[2][CHS], sCi[2][CHS];
    __shared__ float sD0[2][CHS], sD1[2][CHS], sD2[2][CHS];

    const int tid = threadIdx.x;
    const int st  = (tid >= 160) ? 1 : 0;
    const int ts  = tid - st * 160;          // 0..159 within stream

    const int g0   = blockIdx.x * SEGB;
    const int gEnd = min(g0 + SEGB, N_cur);
    const int gMid = min(g0 + SEGB / 2, gEnd);

    const int e00 = (g0   == 0) ? 0 : segEnd[g0 - 1];
    const int e01 = (gMid == 0) ? 0 : segEnd[gMid - 1];
    const int e11 = (gEnd == 0) ? 0 : segEnd[gEnd - 1];

    const int ebeg = st ? e01 : e00;
    const int eend = st ? e11 : e01;

    const int nch0 = (e01 - e00 + CHS - 1) / CHS;
    const int nch1 = (e11 - e01 + CHS - 1) / CHS;
    const int nch  = max(nch0, nch1);

    const int ft = ts * 2;                   // feature pair {ft, ft+1}, ft<=318
    const bool real = (ft < 300);
    float w00 = 0.f, w01 = 0.f, w10 = 0.f, w11 = 0.f, w20 = 0.f, w21 = 0.f;
    float sgn0 = 1.f, sgn1 = 1.f;
    if (real) {
        w00 = Wc[ft];        w01 = Wc[ft + 1];
        w10 = Wc[300 + ft];  w11 = Wc[300 + ft + 1];
        w20 = Wc[600 + ft];  w21 = Wc[600 + ft + 1];
        sgn0 = (g1[ft]     < 0.f) ? -1.f : 1.f;
        sgn1 = (g1[ft + 1] < 0.f) ? -1.f : 1.f;
    }

    int cur = -1;                            // -1 = no open segment
    float m0 = -3.4e38f, m1 = -3.4e38f;
    float sum0 = 0.f, sq0 = 0.f, sum1 = 0.f, sq1 = 0.f;

    for (int ch = 0; ch < nch; ++ch) {
        const int cbeg = ebeg + ch * CHS;
        const int ccnt = min(CHS, eend - cbeg);   // may be <= 0

        for (int i = ts; i < ccnt; i += 160) {
            const int2 r = sorted[cbeg + i];
            sRow[st][i] = r.x * 320;
            sCi[st][i]  = r.y;
            sD0[st][i] = last_coors[r.x * 3 + 0] - cur_coors[r.y * 3 + 0];
            sD1[st][i] = last_coors[r.x * 3 + 1] - cur_coors[r.y * 3 + 1];
            sD2[st][i] = last_coors[r.x * 3 + 2] - cur_coors[r.y * 3 + 2];
        }
        __syncthreads();

        int i = 0;
        for (; i + UNR <= ccnt; i += UNR) {
            unsigned gu[UNR];
            #pragma unroll
            for (int j = 0; j < UNR; ++j)
                gu[j] = *reinterpret_cast<const unsigned*>(&Gb[(long)sRow[st][i + j] + ft]);
            #pragma unroll
            for (int j = 0; j < UNR; ++j) {
                const int ci = sCi[st][i + j];
                if (ci != cur) {               // stream-uniform branch
                    if (cur >= 0)
                        *reinterpret_cast<float2*>(&zbuf[(long)cur * 320 + ft]) =
                            make_float2(m0, m1);
                    cur = ci;
                    m0 = -3.4e38f; m1 = -3.4e38f;
                }
                const float gx = __uint_as_float(gu[j] << 16);
                const float gy = __uint_as_float(gu[j] & 0xffff0000u);
                const float d0 = sD0[st][i + j], d1 = sD1[st][i + j], d2 = sD2[st][i + j];
                const float y0 = fmaxf(gx + d0 * w00 + d1 * w10 + d2 * w20, 0.f);
                const float y1 = fmaxf(gy + d0 * w01 + d1 * w11 + d2 * w21, 0.f);
                sum0 += y0; sq0 += y0 * y0; m0 = fmaxf(m0, sgn0 * y0);
                sum1 += y1; sq1 += y1 * y1; m1 = fmaxf(m1, sgn1 * y1);
            }
        }
        for (; i < ccnt; ++i) {
            const int ci = sCi[st][i];
            if (ci != cur) {
                if (cur >= 0)
                    *reinterpret_cast<float2*>(&zbuf[(long)cur * 320 + ft]) =
                        make_float2(m0, m1);
                cur = ci;
                m0 = -3.4e38f; m1 = -3.4e38f;
            }
            const unsigned gu = *reinterpret_cast<const unsigned*>(&Gb[(long)sRow[st][i] + ft]);
            const float gx = __uint_as_float(gu << 16);
            const float gy = __uint_as_float(gu & 0xffff0000u);
            const float d0 = sD0[st][i], d1 = sD1[st][i], d2 = sD2[st][i];
            const float y0 = fmaxf(gx + d0 * w00 + d1 * w10 + d2 * w20, 0.f);
            const float y1 = fmaxf(gy + d0 * w01 + d1 * w11 + d2 * w21, 0.f);
            sum0 += y0; sq0 += y0 * y0; m0 = fmaxf(m0, sgn0 * y0);
            sum1 += y1; sq1 += y1 * y1; m1 = fmaxf(m1, sgn1 * y1);
        }
        __syncthreads();   // protect LDS before next chunk's staging
    }
    if (cur >= 0)
        *reinterpret_cast<float2*>(&zbuf[(long)cur * 320 + ft]) = make_float2(m0, m1);

    const int slot = blockIdx.x & (NPART - 1);
    if (real) {
        atomicAdd(&part1[slot * 600 + ft],           sum0);
        atomicAdd(&part1[slot * 600 + ft + 1],       sum1);
        atomicAdd(&part1[slot * 600 + 300 + ft],     sq0);
        atomicAdd(&part1[slot * 600 + 300 + ft + 1], sq1);
    }
}

// ---------- reduce partials -> per-feature affine; ac layout a:[0..319] c:[320..639] ----------
__global__ void stats_finalize(const float* __restrict__ part,
                               const float* __restrict__ g,
                               const float* __restrict__ be,
                               float invCnt, float* __restrict__ ac)
{
    const int t = threadIdx.x;   // 320 threads
    if (t >= 300) {
        if (t < 320) { ac[t] = 0.f; ac[320 + t] = 0.f; }   // zero pads
        return;
    }
    float sum = 0.f, sq = 0.f;
    for (int p = 0; p < NPART; ++p) {
        sum += part[p * 600 + t];
        sq  += part[p * 600 + 300 + t];
    }
    const float mean = sum * invCnt;
    const float var = fmaxf(sq * invCnt - mean * mean, 0.f);
    const float inv = rsqrtf(var + 1e-5f);
    const float a = g[t] * inv;
    ac[t] = a;
    ac[320 + t] = be[t] - mean * a;
}

// ---------- apply BN2 affine to d_out in place ----------
__global__ void finalize_out(float* __restrict__ out,
                             const float* __restrict__ ac2)
{
    const int t = threadIdx.x;
    if (t >= 300) return;
    const long i = (long)blockIdx.x * 300 + t;
    out[i] = ac2[t] * out[i] + ac2[320 + t];
}

extern "C" void kernel_launch(void* const* d_in, const int* in_sizes, int n_in,
                              void* d_out, int out_size, void* d_ws, size_t ws_size,
                              hipStream_t stream)
{
    const float* last_coors    = (const float*)d_in[0];
    const float* last_features = (const float*)d_in[1];
    const float* cur_coors     = (const float*)d_in[2];
    const int*   cur_idx       = (const int*)d_in[3];
    const int*   last_idx      = (const int*)d_in[4];
    const float* W1  = (const float*)d_in[5];
    const float* b1  = (const float*)d_in[6];
    const float* g1  = (const float*)d_in[7];
    const float* be1 = (const float*)d_in[8];
    const float* W2  = (const float*)d_in[9];
    const float* b2  = (const float*)d_in[10];
    const float* g2  = (const float*)d_in[11];
    const float* be2 = (const float*)d_in[12];
    float* out = (float*)d_out;

    const int N_last = in_sizes[0] / 3;
    const int N_cur  = in_sizes[2] / 3;
    const int E      = in_sizes[3];

    const int nb1 = (N_cur + SB - 1) / SB;

    // ---- workspace ----
    char* ws = (char*)d_ws;
    size_t off = 0;
    bf16_t* Gb = (bf16_t*)(ws + off);  off += (size_t)N_last * 320 * 2;
    off = (off + 255) & ~(size_t)255;
    float* zbuf = (float*)(ws + off);  off += (size_t)N_cur * 320 * 4;
    off = (off + 255) & ~(size_t)255;
    int2* sorted = (int2*)(ws + off);  off += (size_t)E * 8;
    int* hist = (int*)(ws + off);      off += (size_t)nb1 * SB * 4;
    int* cnt  = (int*)(ws + off);      off += (size_t)nb1 * SB * 4;
    int* bsum = (int*)(ws + off);      off += 256 * 4;
    bf16_t* WT1 = (bf16_t*)(ws + off); off += (size_t)384 * 320 * 2;
    bf16_t* WT2 = (bf16_t*)(ws + off); off += (size_t)384 * 320 * 2;
    float* part1 = (float*)(ws + off); off += (size_t)NPART * 600 * 4;
    float* part2 = (float*)(ws + off); off += (size_t)NPART * 600 * 4;
    float* ac1   = (float*)(ws + off); off += 640 * 4;
    float* ac2   = (float*)(ws + off); off += 640 * 4;

    hipMemsetAsync(hist, 0, (size_t)nb1 * SB * 4, stream);
    hipMemsetAsync(part1, 0, (size_t)2 * NPART * 600 * 4, stream);  // part1+part2

    // ---- counting sort of edges by cur_idx ----
    hist_k<<<(E + 255) / 256, 256, 0, stream>>>(cur_idx, E, hist);
    scan_reduce<<<nb1, SB, 0, stream>>>(hist, N_cur, bsum);
    scan_top<<<1, SB, 0, stream>>>(bsum, nb1);
    scan_final<<<nb1, SB, 0, stream>>>(hist, N_cur, bsum, cnt);
    scatter_k<<<(E + 255) / 256, 256, 0, stream>>>(cur_idx, last_idx, E, cnt, sorted);
    // cnt is now the per-segment END offset array

    // ---- weights ----
    pack_wt2<<<960, 256, 0, stream>>>(W1, W2, WT1);   // WT1,WT2 contiguous

    // gemm0: G = lf @ W1[:300] + b1 (fp32 A read + cvt fused; writes Gb [M][320])
    dim3 gridG(2, (N_last + 127) / 128);
    gemm_mfma<0><<<gridG, 256, 0, stream>>>(last_features, N_last, nullptr, nullptr,
                                            WT1, b1, Gb, nullptr, nullptr);

    // edge pass: one block per SEGB segments; plain float stores to zbuf
    const int nSB = (N_cur + SEGB - 1) / SEGB;
    edge_pass<<<nSB, 320, 0, stream>>>(Gb, last_coors, cur_coors, sorted, cnt,
                                       W1 + 300 * 300, g1, zbuf, part1, N_cur);

    stats_finalize<<<1, 320, 0, stream>>>(part1, g1, be1, 1.0f / (float)E, ac1);

    // gemm1: A = BN1-affine(zbuf) fused in staging; out_pre = ReLU(A@W2+b2) + stats2
    dim3 grid2(2, (N_cur + 127) / 128);
    gemm_mfma<1><<<grid2, 256, 0, stream>>>(zbuf, N_cur, cnt, ac1,
                                            WT2, b2, nullptr, out, part2);

    stats_finalize<<<1, 320, 0, stream>>>(part2, g2, be2, 1.0f / (float)N_cur, ac2);
    finalize_out<<<N_cur, 320, 0, stream>>>(out, ac2);
}

// Round 7
// 548.206 us; speedup vs baseline: 1.1431x; 1.1431x over previous
//
#include <hip/hip_runtime.h>
#include <hip/hip_bf16.h>

// HGNN: out = BN(ReLU( segmax( BN(ReLU(concat(lf[li], dcoor) @ W1 + b1)) ) @ W2 + b2))
//   gemm0: G = lf @ W1[:300] + b1 -> bf16 [N_last][320]; reads fp32 lf DIRECTLY
//          (cvt fused into LDS staging).
//   edge_pass: y = ReLU(G[li] + delta . Wc); counting-sorted edges, block owns
//          SEGB contiguous cur-segments -> plain float2 stores of running max
//          (m = max sgn*y), NO atomics, NO zbuf memset (empty = segEnd gap).
//   gemm1: A = agg = |a1|*m + c1 (BN1 affine, empty rows -> 0) fused into LDS
//          staging from zbuf; out_pre = ReLU(A @ W2 + b2) + stats partials.
//   gemm v3 (traffic fix): FULL-N blocks — 512 thr / 8 waves (2Mx4N), tile
//          128x320, As+Bs both in LDS (~68KB -> 2 blocks/CU); A read from HBM
//          exactly ONCE, Gb lines written whole by one block; B staged from
//          L2-hot WT once per K-step (off the MFMA critical path).
// ac layout: a[c] at ac[c] (c<320, pads 0), offset at ac[320+c] (pads 0).

#define NPART 64
#define SB 256      // scan block
#define SEGB 32     // cur segments owned per edge_pass block (2 streams x 16)
#define CHS 256     // staged edges per stream chunk
#define UNR 8       // edge_pass load batch depth

typedef __bf16 bf16_t;
typedef __bf16 bf16x8 __attribute__((ext_vector_type(8)));
typedef float f32x4 __attribute__((ext_vector_type(4)));

// ---------- counting sort: hist -> scan -> scatter ----------
__global__ void hist_k(const int* __restrict__ ci, int E, int* __restrict__ hist)
{
    const int e = blockIdx.x * 256 + threadIdx.x;
    if (e < E) atomicAdd(&hist[ci[e]], 1);
}

__global__ void scan_reduce(const int* __restrict__ hist, int nseg, int* __restrict__ bsum)
{
    __shared__ int s[SB];
    const int tid = threadIdx.x;
    const int i = blockIdx.x * SB + tid;
    s[tid] = (i < nseg) ? hist[i] : 0;
    __syncthreads();
    for (int o = SB / 2; o > 0; o >>= 1) {
        if (tid < o) s[tid] += s[tid + o];
        __syncthreads();
    }
    if (tid == 0) bsum[blockIdx.x] = s[0];
}

__global__ void scan_top(int* __restrict__ bsum, int nb)
{
    __shared__ int s[SB];
    const int tid = threadIdx.x;
    const int v = (tid < nb) ? bsum[tid] : 0;
    s[tid] = v;
    __syncthreads();
    for (int o = 1; o < SB; o <<= 1) {
        int x = 0;
        if (tid >= o) x = s[tid - o];
        __syncthreads();
        s[tid] += x;
        __syncthreads();
    }
    if (tid < nb) bsum[tid] = s[tid] - v;   // exclusive
}

__global__ void scan_final(const int* __restrict__ hist, int nseg,
                           const int* __restrict__ bsum, int* __restrict__ cnt)
{
    __shared__ int s[SB];
    const int tid = threadIdx.x;
    const int i = blockIdx.x * SB + tid;
    const int v = (i < nseg) ? hist[i] : 0;
    s[tid] = v;
    __syncthreads();
    for (int o = 1; o < SB; o <<= 1) {
        int x = 0;
        if (tid >= o) x = s[tid - o];
        __syncthreads();
        s[tid] += x;
        __syncthreads();
    }
    if (i < nseg) cnt[i] = s[tid] - v + bsum[blockIdx.x];
}

__global__ void scatter_k(const int* __restrict__ ci, const int* __restrict__ li,
                          int E, int* __restrict__ cnt, int2* __restrict__ sorted)
{
    const int e = blockIdx.x * 256 + threadIdx.x;
    if (e >= E) return;
    const int c = ci[e];
    const int pos = atomicAdd(&cnt[c], 1);
    sorted[pos] = make_int2(li[e], c);
    // after this kernel: cnt[c] = END offset of segment c in sorted[]
}

// ---------- pack BOTH W (fp32 [300][300] row-major) -> WT bf16 [2][384][320] ----------
__global__ void pack_wt2(const float* __restrict__ W1, const float* __restrict__ W2,
                         bf16_t* __restrict__ WT)
{
    const int idx = blockIdx.x * 256 + threadIdx.x;
    if (idx >= 2 * 384 * 320) return;
    const int w = idx / (384 * 320);
    const int rem = idx - w * (384 * 320);
    const int n = rem / 320, k = rem % 320;
    const float* W = w ? W2 : W1;
    float v = (n < 300 && k < 300) ? W[k * 300 + n] : 0.f;
    WT[idx] = (bf16_t)v;
}

// ---------- MFMA bf16 GEMM, full-N blocks, fused A-staging transform ----------
// 512 threads = 8 waves (2M x 4N). Tile 128 (M) x 320 (all N), BK=64.
// MODE 0: A32 = lf fp32 [M][300]; stage cvt->bf16 (zero-pad cols>=300);
//         epilogue: +bias, bf16 [M][320] to outBF (pad cols zeroed).
// MODE 1: A32 = zbuf float [M][320] (seg running max m); stage
//         v = empty(r) ? 0 : |ac[c]|*m + ac[320+c]  (ac pads are 0, via LDS);
//         epilogue: ReLU(+bias), fp32 [M][300] to outF, stats partials.
template<int MODE>
__launch_bounds__(512, 4)
__global__ void gemm_mfma(const float* __restrict__ A32, int M,
                          const int* __restrict__ segEnd,   // MODE 1
                          const float* __restrict__ ac,     // MODE 1 (640 floats)
                          const bf16_t* __restrict__ WT,
                          const float* __restrict__ bias,
                          bf16_t* __restrict__ outBF,
                          float* __restrict__ outF,
                          float* __restrict__ part)
{
    __shared__ bf16_t As[128][72];
    __shared__ bf16_t Bs[320][72];
    __shared__ float sSum[320], sSq[320];
    __shared__ float sAc[640];

    const int tid  = threadIdx.x;
    const int lane = tid & 63, wv = tid >> 6;     // 8 waves
    const int wm = wv & 1, wn = wv >> 1;          // 2 (M) x 4 (N)
    const int m0 = blockIdx.x * 128;
    const int rl = lane & 15, quad = lane >> 4;

    if (MODE == 1) {
        if (tid < 320) { sSum[tid] = 0.f; sSq[tid] = 0.f; }
        for (int i = tid; i < 640; i += 512) sAc[i] = ac[i];
    }

    // staging geometry: thread owns col-chunk kcT (8 cols); A rows rT, rT+64;
    // B rows rT + i*64 for i in 0..4.
    const int kcT = (tid & 7) * 8;
    const int rT  = tid >> 3;            // 0..63
    int growA[2]; bool emp[2];
    #pragma unroll
    for (int i = 0; i < 2; ++i) {
        growA[i] = min(m0 + i * 64 + rT, M - 1);
        emp[i] = false;
        if (MODE == 1)
            emp[i] = segEnd[growA[i]] == (growA[i] ? segEnd[growA[i] - 1] : 0);
    }

    f32x4 acc[4][5];
    #pragma unroll
    for (int i = 0; i < 4; ++i)
        #pragma unroll
        for (int j = 0; j < 5; ++j)
            acc[i][j] = (f32x4){0.f, 0.f, 0.f, 0.f};

    if (MODE == 1) __syncthreads();   // sAc ready

    for (int k0 = 0; k0 < 320; k0 += 64) {
        const int c0 = k0 + kcT;

        // ---- issue all global loads first (A: HBM, B: L2-hot WT) ----
        float4 la[2], lb[2];
        #pragma unroll
        for (int i = 0; i < 2; ++i) {
            la[i] = make_float4(0.f, 0.f, 0.f, 0.f);
            lb[i] = make_float4(0.f, 0.f, 0.f, 0.f);
            if (MODE == 0) {
                if (c0 + 8 <= 300) {
                    la[i] = *reinterpret_cast<const float4*>(&A32[(long)growA[i] * 300 + c0]);
                    lb[i] = *reinterpret_cast<const float4*>(&A32[(long)growA[i] * 300 + c0 + 4]);
                } else if (c0 < 300) {   // c0 == 296
                    la[i] = *reinterpret_cast<const float4*>(&A32[(long)growA[i] * 300 + c0]);
                }
            } else {
                la[i] = *reinterpret_cast<const float4*>(&A32[(long)growA[i] * 320 + c0]);
                lb[i] = *reinterpret_cast<const float4*>(&A32[(long)growA[i] * 320 + c0 + 4]);
            }
        }
        bf16x8 wb[5];
        #pragma unroll
        for (int i = 0; i < 5; ++i)
            wb[i] = *reinterpret_cast<const bf16x8*>(&WT[(long)(i * 64 + rT) * 320 + c0]);

        // ---- transform + LDS stores ----
        #pragma unroll
        for (int i = 0; i < 2; ++i) {
            bf16x8 v;
            if (MODE == 0) {
                v = (bf16x8){(bf16_t)la[i].x, (bf16_t)la[i].y, (bf16_t)la[i].z, (bf16_t)la[i].w,
                             (bf16_t)lb[i].x, (bf16_t)lb[i].y, (bf16_t)lb[i].z, (bf16_t)lb[i].w};
            } else {
                const float4 aa = *reinterpret_cast<const float4*>(&sAc[c0]);
                const float4 ab = *reinterpret_cast<const float4*>(&sAc[c0 + 4]);
                const float4 ca = *reinterpret_cast<const float4*>(&sAc[320 + c0]);
                const float4 cb = *reinterpret_cast<const float4*>(&sAc[320 + c0 + 4]);
                const float t0 = emp[i] ? 0.f : fabsf(aa.x) * la[i].x + ca.x;
                const float t1 = emp[i] ? 0.f : fabsf(aa.y) * la[i].y + ca.y;
                const float t2 = emp[i] ? 0.f : fabsf(aa.z) * la[i].z + ca.z;
                const float t3 = emp[i] ? 0.f : fabsf(aa.w) * la[i].w + ca.w;
                const float t4 = emp[i] ? 0.f : fabsf(ab.x) * lb[i].x + cb.x;
                const float t5 = emp[i] ? 0.f : fabsf(ab.y) * lb[i].y + cb.y;
                const float t6 = emp[i] ? 0.f : fabsf(ab.z) * lb[i].z + cb.z;
                const float t7 = emp[i] ? 0.f : fabsf(ab.w) * lb[i].w + cb.w;
                v = (bf16x8){(bf16_t)t0, (bf16_t)t1, (bf16_t)t2, (bf16_t)t3,
                             (bf16_t)t4, (bf16_t)t5, (bf16_t)t6, (bf16_t)t7};
            }
            *reinterpret_cast<bf16x8*>(&As[i * 64 + rT][kcT]) = v;
        }
        #pragma unroll
        for (int i = 0; i < 5; ++i)
            *reinterpret_cast<bf16x8*>(&Bs[i * 64 + rT][kcT]) = wb[i];
        __syncthreads();

        // ---- compute ----
        #pragma unroll
        for (int kk = 0; kk < 2; ++kk) {
            const int kb = kk * 32 + quad * 8;
            bf16x8 af[4], bfr[5];
            #pragma unroll
            for (int mi = 0; mi < 4; ++mi)
                af[mi] = *reinterpret_cast<const bf16x8*>(&As[wm * 64 + mi * 16 + rl][kb]);
            #pragma unroll
            for (int nj = 0; nj < 5; ++nj)
                bfr[nj] = *reinterpret_cast<const bf16x8*>(&Bs[wn * 80 + nj * 16 + rl][kb]);
            #pragma unroll
            for (int mi = 0; mi < 4; ++mi)
                #pragma unroll
                for (int nj = 0; nj < 5; ++nj)
                    acc[mi][nj] = __builtin_amdgcn_mfma_f32_16x16x32_bf16(
                        af[mi], bfr[nj], acc[mi][nj], 0, 0, 0);
        }
        __syncthreads();
    }

    // epilogue: C/D layout col = lane&15, row = quad*4 + reg
    if (MODE == 0) {
        #pragma unroll
        for (int mi = 0; mi < 4; ++mi)
            #pragma unroll
            for (int nj = 0; nj < 5; ++nj)
                #pragma unroll
                for (int reg = 0; reg < 4; ++reg) {
                    const int r = m0 + wm * 64 + mi * 16 + quad * 4 + reg;
                    const int c = wn * 80 + nj * 16 + rl;   // < 320
                    if (r < M) {
                        const float v = (c < 300) ? (acc[mi][nj][reg] + bias[c]) : 0.f;
                        outBF[(long)r * 320 + c] = (bf16_t)v;
                    }
                }
    } else {
        float csum[5] = {}, csq[5] = {};
        #pragma unroll
        for (int mi = 0; mi < 4; ++mi)
            #pragma unroll
            for (int nj = 0; nj < 5; ++nj)
                #pragma unroll
                for (int reg = 0; reg < 4; ++reg) {
                    const int r = m0 + wm * 64 + mi * 16 + quad * 4 + reg;
                    const int c = wn * 80 + nj * 16 + rl;
                    if (r < M && c < 300) {
                        float v = fmaxf(acc[mi][nj][reg] + bias[c], 0.f);
                        outF[(long)r * 300 + c] = v;
                        csum[nj] += v; csq[nj] += v * v;
                    }
                }
        #pragma unroll
        for (int nj = 0; nj < 5; ++nj) {
            const int cl = wn * 80 + nj * 16 + rl;
            if (cl < 300) {
                atomicAdd(&sSum[cl], csum[nj]);
                atomicAdd(&sSq[cl], csq[nj]);
            }
        }
        __syncthreads();
        const int slot = blockIdx.x & (NPART - 1);
        if (tid < 300) {
            atomicAdd(&part[slot * 600 + tid], sSum[tid]);
            atomicAdd(&part[slot * 600 + 300 + tid], sSq[tid]);
        }
    }
}

// ---------- edge pass: block owns SEGB contiguous segments; plain float stores ----------
__launch_bounds__(320)
__global__ void edge_pass(const bf16_t* __restrict__ Gb,   // [N_last][320]
                          const float* __restrict__ last_coors,
                          const float* __restrict__ cur_coors,
                          const int2* __restrict__ sorted,  // (li, ci), sorted by ci
                          const int*  __restrict__ segEnd,  // end offsets per cur node
                          const float* __restrict__ Wc,     // rows 300..302 of W1, 3x300
                          const float* __restrict__ g1,
                          float* __restrict__ zbuf,         // [N_cur][320] raw max (m)
                          float* __restrict__ part1,
                          int N_cur)
{
    __shared__ int sRow[2][CHS], sCi[2][CHS];
    __shared__ float sD0[2][CHS], sD1[2][CHS], sD2[2][CHS];

    const int tid = threadIdx.x;
    const int st  = (tid >= 160) ? 1 : 0;
    const int ts  = tid - st * 160;          // 0..159 within stream

    const int g0   = blockIdx.x * SEGB;
    const int gEnd = min(g0 + SEGB, N_cur);
    const int gMid = min(g0 + SEGB / 2, gEnd);

    const int e00 = (g0   == 0) ? 0 : segEnd[g0 - 1];
    const int e01 = (gMid == 0) ? 0 : segEnd[gMid - 1];
    const int e11 = (gEnd == 0) ? 0 : segEnd[gEnd - 1];

    const int ebeg = st ? e01 : e00;
    const int eend = st ? e11 : e01;

    const int nch0 = (e01 - e00 + CHS - 1) / CHS;
    const int nch1 = (e11 - e01 + CHS - 1) / CHS;
    const int nch  = max(nch0, nch1);

    const int ft = ts * 2;                   // feature pair {ft, ft+1}, ft<=318
    const bool real = (ft < 300);
    float w00 = 0.f, w01 = 0.f, w10 = 0.f, w11 = 0.f, w20 = 0.f, w21 = 0.f;
    float sgn0 = 1.f, sgn1 = 1.f;
    if (real) {
        w00 = Wc[ft];        w01 = Wc[ft + 1];
        w10 = Wc[300 + ft];  w11 = Wc[300 + ft + 1];
        w20 = Wc[600 + ft];  w21 = Wc[600 + ft + 1];
        sgn0 = (g1[ft]     < 0.f) ? -1.f : 1.f;
        sgn1 = (g1[ft + 1] < 0.f) ? -1.f : 1.f;
    }

    int cur = -1;                            // -1 = no open segment
    float m0 = -3.4e38f, m1 = -3.4e38f;
    float sum0 = 0.f, sq0 = 0.f, sum1 = 0.f, sq1 = 0.f;

    for (int ch = 0; ch < nch; ++ch) {
        const int cbeg = ebeg + ch * CHS;
        const int ccnt = min(CHS, eend - cbeg);   // may be <= 0

        for (int i = ts; i < ccnt; i += 160) {
            const int2 r = sorted[cbeg + i];
            sRow[st][i] = r.x * 320;
            sCi[st][i]  = r.y;
            sD0[st][i] = last_coors[r.x * 3 + 0] - cur_coors[r.y * 3 + 0];
            sD1[st][i] = last_coors[r.x * 3 + 1] - cur_coors[r.y * 3 + 1];
            sD2[st][i] = last_coors[r.x * 3 + 2] - cur_coors[r.y * 3 + 2];
        }
        __syncthreads();

        int i = 0;
        for (; i + UNR <= ccnt; i += UNR) {
            unsigned gu[UNR];
            #pragma unroll
            for (int j = 0; j < UNR; ++j)
                gu[j] = *reinterpret_cast<const unsigned*>(&Gb[(long)sRow[st][i + j] + ft]);
            #pragma unroll
            for (int j = 0; j < UNR; ++j) {
                const int ci = sCi[st][i + j];
                if (ci != cur) {               // stream-uniform branch
                    if (cur >= 0)
                        *reinterpret_cast<float2*>(&zbuf[(long)cur * 320 + ft]) =
                            make_float2(m0, m1);
                    cur = ci;
                    m0 = -3.4e38f; m1 = -3.4e38f;
                }
                const float gx = __uint_as_float(gu[j] << 16);
                const float gy = __uint_as_float(gu[j] & 0xffff0000u);
                const float d0 = sD0[st][i + j], d1 = sD1[st][i + j], d2 = sD2[st][i + j];
                const float y0 = fmaxf(gx + d0 * w00 + d1 * w10 + d2 * w20, 0.f);
                const float y1 = fmaxf(gy + d0 * w01 + d1 * w11 + d2 * w21, 0.f);
                sum0 += y0; sq0 += y0 * y0; m0 = fmaxf(m0, sgn0 * y0);
                sum1 += y1; sq1 += y1 * y1; m1 = fmaxf(m1, sgn1 * y1);
            }
        }
        for (; i < ccnt; ++i) {
            const int ci = sCi[st][i];
            if (ci != cur) {
                if (cur >= 0)
                    *reinterpret_cast<float2*>(&zbuf[(long)cur * 320 + ft]) =
                        make_float2(m0, m1);
                cur = ci;
                m0 = -3.4e38f; m1 = -3.4e38f;
            }
            const unsigned gu = *reinterpret_cast<const unsigned*>(&Gb[(long)sRow[st][i] + ft]);
            const float gx = __uint_as_float(gu << 16);
            const float gy = __uint_as_float(gu & 0xffff0000u);
            const float d0 = sD0[st][i], d1 = sD1[st][i], d2 = sD2[st][i];
            const float y0 = fmaxf(gx + d0 * w00 + d1 * w10 + d2 * w20, 0.f);
            const float y1 = fmaxf(gy + d0 * w01 + d1 * w11 + d2 * w21, 0.f);
            sum0 += y0; sq0 += y0 * y0; m0 = fmaxf(m0, sgn0 * y0);
            sum1 += y1; sq1 += y1 * y1; m1 = fmaxf(m1, sgn1 * y1);
        }
        __syncthreads();   // protect LDS before next chunk's staging
    }
    if (cur >= 0)
        *reinterpret_cast<float2*>(&zbuf[(long)cur * 320 + ft]) = make_float2(m0, m1);

    const int slot = blockIdx.x & (NPART - 1);
    if (real) {
        atomicAdd(&part1[slot * 600 + ft],           sum0);
        atomicAdd(&part1[slot * 600 + ft + 1],       sum1);
        atomicAdd(&part1[slot * 600 + 300 + ft],     sq0);
        atomicAdd(&part1[slot * 600 + 300 + ft + 1], sq1);
    }
}

// ---------- reduce partials -> per-feature affine; ac layout a:[0..319] c:[320..639] ----------
__global__ void stats_finalize(const float* __restrict__ part,
                               const float* __restrict__ g,
                               const float* __restrict__ be,
                               float invCnt, float* __restrict__ ac)
{
    const int t = threadIdx.x;   // 320 threads
    if (t >= 300) {
        if (t < 320) { ac[t] = 0.f; ac[320 + t] = 0.f; }   // zero pads
        return;
    }
    float sum = 0.f, sq = 0.f;
    for (int p = 0; p < NPART; ++p) {
        sum += part[p * 600 + t];
        sq  += part[p * 600 + 300 + t];
    }
    const float mean = sum * invCnt;
    const float var = fmaxf(sq * invCnt - mean * mean, 0.f);
    const float inv = rsqrtf(var + 1e-5f);
    const float a = g[t] * inv;
    ac[t] = a;
    ac[320 + t] = be[t] - mean * a;
}

// ---------- apply BN2 affine to d_out in place ----------
__global__ void finalize_out(float* __restrict__ out,
                             const float* __restrict__ ac2)
{
    const int t = threadIdx.x;
    if (t >= 300) return;
    const long i = (long)blockIdx.x * 300 + t;
    out[i] = ac2[t] * out[i] + ac2[320 + t];
}

extern "C" void kernel_launch(void* const* d_in, const int* in_sizes, int n_in,
                              void* d_out, int out_size, void* d_ws, size_t ws_size,
                              hipStream_t stream)
{
    const float* last_coors    = (const float*)d_in[0];
    const float* last_features = (const float*)d_in[1];
    const float* cur_coors     = (const float*)d_in[2];
    const int*   cur_idx       = (const int*)d_in[3];
    const int*   last_idx      = (const int*)d_in[4];
    const float* W1  = (const float*)d_in[5];
    const float* b1  = (const float*)d_in[6];
    const float* g1  = (const float*)d_in[7];
    const float* be1 = (const float*)d_in[8];
    const float* W2  = (const float*)d_in[9];
    const float* b2  = (const float*)d_in[10];
    const float* g2  = (const float*)d_in[11];
    const float* be2 = (const float*)d_in[12];
    float* out = (float*)d_out;

    const int N_last = in_sizes[0] / 3;
    const int N_cur  = in_sizes[2] / 3;
    const int E      = in_sizes[3];

    const int nb1 = (N_cur + SB - 1) / SB;

    // ---- workspace ----
    char* ws = (char*)d_ws;
    size_t off = 0;
    bf16_t* Gb = (bf16_t*)(ws + off);  off += (size_t)N_last * 320 * 2;
    off = (off + 255) & ~(size_t)255;
    float* zbuf = (float*)(ws + off);  off += (size_t)N_cur * 320 * 4;
    off = (off + 255) & ~(size_t)255;
    int2* sorted = (int2*)(ws + off);  off += (size_t)E * 8;
    int* hist = (int*)(ws + off);      off += (size_t)nb1 * SB * 4;
    int* cnt  = (int*)(ws + off);      off += (size_t)nb1 * SB * 4;
    int* bsum = (int*)(ws + off);      off += 256 * 4;
    bf16_t* WT1 = (bf16_t*)(ws + off); off += (size_t)384 * 320 * 2;
    bf16_t* WT2 = (bf16_t*)(ws + off); off += (size_t)384 * 320 * 2;
    float* part1 = (float*)(ws + off); off += (size_t)NPART * 600 * 4;
    float* part2 = (float*)(ws + off); off += (size_t)NPART * 600 * 4;
    float* ac1   = (float*)(ws + off); off += 640 * 4;
    float* ac2   = (float*)(ws + off); off += 640 * 4;

    hipMemsetAsync(hist, 0, (size_t)nb1 * SB * 4, stream);
    hipMemsetAsync(part1, 0, (size_t)2 * NPART * 600 * 4, stream);  // part1+part2

    // ---- counting sort of edges by cur_idx ----
    hist_k<<<(E + 255) / 256, 256, 0, stream>>>(cur_idx, E, hist);
    scan_reduce<<<nb1, SB, 0, stream>>>(hist, N_cur, bsum);
    scan_top<<<1, SB, 0, stream>>>(bsum, nb1);
    scan_final<<<nb1, SB, 0, stream>>>(hist, N_cur, bsum, cnt);
    scatter_k<<<(E + 255) / 256, 256, 0, stream>>>(cur_idx, last_idx, E, cnt, sorted);
    // cnt is now the per-segment END offset array

    // ---- weights ----
    pack_wt2<<<960, 256, 0, stream>>>(W1, W2, WT1);   // WT1,WT2 contiguous

    // gemm0: G = lf @ W1[:300] + b1 (fp32 A read + cvt fused; writes Gb [M][320])
    gemm_mfma<0><<<(N_last + 127) / 128, 512, 0, stream>>>(
        last_features, N_last, nullptr, nullptr, WT1, b1, Gb, nullptr, nullptr);

    // edge pass: one block per SEGB segments; plain float stores to zbuf
    const int nSB = (N_cur + SEGB - 1) / SEGB;
    edge_pass<<<nSB, 320, 0, stream>>>(Gb, last_coors, cur_coors, sorted, cnt,
                                       W1 + 300 * 300, g1, zbuf, part1, N_cur);

    stats_finalize<<<1, 320, 0, stream>>>(part1, g1, be1, 1.0f / (float)E, ac1);

    // gemm1: A = BN1-affine(zbuf) fused in staging; out_pre = ReLU(A@W2+b2) + stats2
    gemm_mfma<1><<<(N_cur + 127) / 128, 512, 0, stream>>>(
        zbuf, N_cur, cnt, ac1, WT2, b2, nullptr, out, part2);

    stats_finalize<<<1, 320, 0, stream>>>(part2, g2, be2, 1.0f / (float)N_cur, ac2);
    finalize_out<<<N_cur, 320, 0, stream>>>(out, ac2);
}

// Round 8
// 537.342 us; speedup vs baseline: 1.1662x; 1.0202x over previous
//
#include <hip/hip_runtime.h>
#include <hip/hip_bf16.h>

// HGNN: out = BN(ReLU( segmax( BN(ReLU(concat(lf[li], dcoor) @ W1 + b1)) ) @ W2 + b2))
//   gemm0: G = lf @ W1[:300] + b1 -> bf16 [N_last][320]; fp32 lf read ONCE
//          (cvt fused into staging).
//   edge_pass: y = ReLU(G[li] + delta . Wc); counting-sorted edges, block owns
//          SEGB contiguous cur-segments -> plain float2 stores of running max
//          (m = max sgn*y), NO atomics, NO zbuf memset (empty = segEnd gap).
//   gemm1: A = |a1|*m + c1 (BN1 affine, empty rows -> 0) fused into staging
//          from zbuf; out_pre = ReLU(A @ W2 + b2) + stats partials.
//   gemm v4 (duty fix): 256 thr / 4 waves, tile 64M x 320N (full N, A read
//          once); B fragments DIRECT from L2-hot WT (no Bs LDS, r6-proven);
//          As double-buffered [2][64][72] (~23KB -> ~3 blocks/CU); 2-phase
//          prefetch: step t+1's A loads issued BEFORE compute of step t,
//          cvt+ds_write after, ONE barrier per K-step (write buf != read buf).
// ac layout: a[c] at ac[c] (c<320, pads 0), offset at ac[320+c] (pads 0).

#define NPART 64
#define SB 256      // scan block
#define SEGB 32     // cur segments owned per edge_pass block (2 streams x 16)
#define CHS 256     // staged edges per stream chunk
#define UNR 8       // edge_pass load batch depth

typedef __bf16 bf16_t;
typedef __bf16 bf16x8 __attribute__((ext_vector_type(8)));
typedef float f32x4 __attribute__((ext_vector_type(4)));

// ---------- counting sort: hist -> scan -> scatter ----------
__global__ void hist_k(const int* __restrict__ ci, int E, int* __restrict__ hist)
{
    const int e = blockIdx.x * 256 + threadIdx.x;
    if (e < E) atomicAdd(&hist[ci[e]], 1);
}

__global__ void scan_reduce(const int* __restrict__ hist, int nseg, int* __restrict__ bsum)
{
    __shared__ int s[SB];
    const int tid = threadIdx.x;
    const int i = blockIdx.x * SB + tid;
    s[tid] = (i < nseg) ? hist[i] : 0;
    __syncthreads();
    for (int o = SB / 2; o > 0; o >>= 1) {
        if (tid < o) s[tid] += s[tid + o];
        __syncthreads();
    }
    if (tid == 0) bsum[blockIdx.x] = s[0];
}

__global__ void scan_top(int* __restrict__ bsum, int nb)
{
    __shared__ int s[SB];
    const int tid = threadIdx.x;
    const int v = (tid < nb) ? bsum[tid] : 0;
    s[tid] = v;
    __syncthreads();
    for (int o = 1; o < SB; o <<= 1) {
        int x = 0;
        if (tid >= o) x = s[tid - o];
        __syncthreads();
        s[tid] += x;
        __syncthreads();
    }
    if (tid < nb) bsum[tid] = s[tid] - v;   // exclusive
}

__global__ void scan_final(const int* __restrict__ hist, int nseg,
                           const int* __restrict__ bsum, int* __restrict__ cnt)
{
    __shared__ int s[SB];
    const int tid = threadIdx.x;
    const int i = blockIdx.x * SB + tid;
    const int v = (i < nseg) ? hist[i] : 0;
    s[tid] = v;
    __syncthreads();
    for (int o = 1; o < SB; o <<= 1) {
        int x = 0;
        if (tid >= o) x = s[tid - o];
        __syncthreads();
        s[tid] += x;
        __syncthreads();
    }
    if (i < nseg) cnt[i] = s[tid] - v + bsum[blockIdx.x];
}

__global__ void scatter_k(const int* __restrict__ ci, const int* __restrict__ li,
                          int E, int* __restrict__ cnt, int2* __restrict__ sorted)
{
    const int e = blockIdx.x * 256 + threadIdx.x;
    if (e >= E) return;
    const int c = ci[e];
    const int pos = atomicAdd(&cnt[c], 1);
    sorted[pos] = make_int2(li[e], c);
    // after this kernel: cnt[c] = END offset of segment c in sorted[]
}

// ---------- pack BOTH W (fp32 [300][300] row-major) -> WT bf16 [2][384][320] ----------
__global__ void pack_wt2(const float* __restrict__ W1, const float* __restrict__ W2,
                         bf16_t* __restrict__ WT)
{
    const int idx = blockIdx.x * 256 + threadIdx.x;
    if (idx >= 2 * 384 * 320) return;
    const int w = idx / (384 * 320);
    const int rem = idx - w * (384 * 320);
    const int n = rem / 320, k = rem % 320;
    const float* W = w ? W2 : W1;
    float v = (n < 300 && k < 300) ? W[k * 300 + n] : 0.f;
    WT[idx] = (bf16_t)v;
}

// ---------- MFMA bf16 GEMM, full-N, double-buffered A, B-direct ----------
// 256 threads = 4 waves; wave wn owns N cols [wn*80, wn*80+80); block owns
// 64 M rows. K = 320, BK = 64, 5 steps, fully unrolled, 2-phase prefetch.
// MODE 0: A32 = lf fp32 [M][300]; stage cvt->bf16 (zero-pad cols>=300);
//         epilogue: +bias, bf16 [M][320] to outBF (pad cols zeroed).
// MODE 1: A32 = zbuf float [M][320]; stage v = empty ? 0 : |a|*m + c (LDS ac);
//         epilogue: ReLU(+bias), fp32 [M][300] to outF, stats partials.
template<int MODE>
__launch_bounds__(256, 3)
__global__ void gemm_mfma(const float* __restrict__ A32, int M,
                          const int* __restrict__ segEnd,   // MODE 1
                          const float* __restrict__ ac,     // MODE 1 (640 floats)
                          const bf16_t* __restrict__ WT,
                          const float* __restrict__ bias,
                          bf16_t* __restrict__ outBF,
                          float* __restrict__ outF,
                          float* __restrict__ part)
{
    __shared__ bf16_t As[2][64][72];
    __shared__ float sSum[320], sSq[320];
    __shared__ float sAc[640];

    const int tid  = threadIdx.x;
    const int lane = tid & 63, wn = tid >> 6;     // 4 waves over N
    const int m0 = blockIdx.x * 64;
    const int rl = lane & 15, quad = lane >> 4;

    // staging geometry: thread owns col-chunk kcT (8 cols) of rows rT, rT+32
    const int kcT = (tid & 7) * 8;
    const int rT  = tid >> 3;                      // 0..31
    int grow[2]; bool emp[2];
    #pragma unroll
    for (int i = 0; i < 2; ++i) {
        grow[i] = min(m0 + i * 32 + rT, M - 1);
        emp[i] = false;
        if (MODE == 1)
            emp[i] = segEnd[grow[i]] == (grow[i] ? segEnd[grow[i] - 1] : 0);
    }

    if (MODE == 1) {
        for (int i = tid; i < 320; i += 256) { sSum[i] = 0.f; sSq[i] = 0.f; }
        for (int i = tid; i < 640; i += 256) sAc[i] = ac[i];
    }

    auto LOADA = [&](int k0p, float4* la, float4* lb) {
        const int c0 = k0p + kcT;
        #pragma unroll
        for (int i = 0; i < 2; ++i) {
            la[i] = make_float4(0.f, 0.f, 0.f, 0.f);
            lb[i] = make_float4(0.f, 0.f, 0.f, 0.f);
            if (MODE == 0) {
                if (c0 + 8 <= 300) {
                    la[i] = *reinterpret_cast<const float4*>(&A32[(long)grow[i] * 300 + c0]);
                    lb[i] = *reinterpret_cast<const float4*>(&A32[(long)grow[i] * 300 + c0 + 4]);
                } else if (c0 < 300) {   // c0 == 296
                    la[i] = *reinterpret_cast<const float4*>(&A32[(long)grow[i] * 300 + c0]);
                }
            } else {
                la[i] = *reinterpret_cast<const float4*>(&A32[(long)grow[i] * 320 + c0]);
                lb[i] = *reinterpret_cast<const float4*>(&A32[(long)grow[i] * 320 + c0 + 4]);
            }
        }
    };
    auto STOREA = [&](int buf, int k0p, const float4* la, const float4* lb) {
        const int c0 = k0p + kcT;
        #pragma unroll
        for (int i = 0; i < 2; ++i) {
            bf16x8 v;
            if (MODE == 0) {
                v = (bf16x8){(bf16_t)la[i].x, (bf16_t)la[i].y, (bf16_t)la[i].z, (bf16_t)la[i].w,
                             (bf16_t)lb[i].x, (bf16_t)lb[i].y, (bf16_t)lb[i].z, (bf16_t)lb[i].w};
            } else {
                const float4 aa = *reinterpret_cast<const float4*>(&sAc[c0]);
                const float4 ab = *reinterpret_cast<const float4*>(&sAc[c0 + 4]);
                const float4 ca = *reinterpret_cast<const float4*>(&sAc[320 + c0]);
                const float4 cb = *reinterpret_cast<const float4*>(&sAc[320 + c0 + 4]);
                const float t0 = emp[i] ? 0.f : fabsf(aa.x) * la[i].x + ca.x;
                const float t1 = emp[i] ? 0.f : fabsf(aa.y) * la[i].y + ca.y;
                const float t2 = emp[i] ? 0.f : fabsf(aa.z) * la[i].z + ca.z;
                const float t3 = emp[i] ? 0.f : fabsf(aa.w) * la[i].w + ca.w;
                const float t4 = emp[i] ? 0.f : fabsf(ab.x) * lb[i].x + cb.x;
                const float t5 = emp[i] ? 0.f : fabsf(ab.y) * lb[i].y + cb.y;
                const float t6 = emp[i] ? 0.f : fabsf(ab.z) * lb[i].z + cb.z;
                const float t7 = emp[i] ? 0.f : fabsf(ab.w) * lb[i].w + cb.w;
                v = (bf16x8){(bf16_t)t0, (bf16_t)t1, (bf16_t)t2, (bf16_t)t3,
                             (bf16_t)t4, (bf16_t)t5, (bf16_t)t6, (bf16_t)t7};
            }
            *reinterpret_cast<bf16x8*>(&As[buf][i * 32 + rT][kcT]) = v;
        }
    };

    f32x4 acc[4][5];
    #pragma unroll
    for (int i = 0; i < 4; ++i)
        #pragma unroll
        for (int j = 0; j < 5; ++j)
            acc[i][j] = (f32x4){0.f, 0.f, 0.f, 0.f};

    // prologue: stage tile 0
    {
        float4 la[2], lb[2];
        LOADA(0, la, lb);
        if (MODE == 1) __syncthreads();   // sAc visible before STOREA uses it
        STOREA(0, 0, la, lb);
    }
    __syncthreads();

    #pragma unroll
    for (int t = 0; t < 5; ++t) {
        const int cb = t & 1, nb = (t + 1) & 1;
        const int k0 = t * 64;
        float4 la[2], lb[2];
        if (t + 1 < 5) LOADA((t + 1) * 64, la, lb);   // prefetch next tile

        // compute step t from As[cb]; B direct from L2-hot WT
        #pragma unroll
        for (int kk = 0; kk < 2; ++kk) {
            const int kb = kk * 32 + quad * 8;
            bf16x8 af[4], bfr[5];
            #pragma unroll
            for (int nj = 0; nj < 5; ++nj)
                bfr[nj] = *reinterpret_cast<const bf16x8*>(
                    &WT[(long)(wn * 80 + nj * 16 + rl) * 320 + k0 + kb]);
            #pragma unroll
            for (int mi = 0; mi < 4; ++mi)
                af[mi] = *reinterpret_cast<const bf16x8*>(&As[cb][mi * 16 + rl][kb]);
            #pragma unroll
            for (int mi = 0; mi < 4; ++mi)
                #pragma unroll
                for (int nj = 0; nj < 5; ++nj)
                    acc[mi][nj] = __builtin_amdgcn_mfma_f32_16x16x32_bf16(
                        af[mi], bfr[nj], acc[mi][nj], 0, 0, 0);
        }

        if (t + 1 < 5) STOREA(nb, (t + 1) * 64, la, lb);   // write buf != read buf
        __syncthreads();
    }

    // epilogue: C/D layout col = lane&15, row = quad*4 + reg
    if (MODE == 0) {
        #pragma unroll
        for (int mi = 0; mi < 4; ++mi)
            #pragma unroll
            for (int nj = 0; nj < 5; ++nj)
                #pragma unroll
                for (int reg = 0; reg < 4; ++reg) {
                    const int r = m0 + mi * 16 + quad * 4 + reg;
                    const int c = wn * 80 + nj * 16 + rl;   // < 320
                    if (r < M) {
                        const float v = (c < 300) ? (acc[mi][nj][reg] + bias[c]) : 0.f;
                        outBF[(long)r * 320 + c] = (bf16_t)v;
                    }
                }
    } else {
        float csum[5] = {}, csq[5] = {};
        #pragma unroll
        for (int mi = 0; mi < 4; ++mi)
            #pragma unroll
            for (int nj = 0; nj < 5; ++nj)
                #pragma unroll
                for (int reg = 0; reg < 4; ++reg) {
                    const int r = m0 + mi * 16 + quad * 4 + reg;
                    const int c = wn * 80 + nj * 16 + rl;
                    if (r < M && c < 300) {
                        float v = fmaxf(acc[mi][nj][reg] + bias[c], 0.f);
                        outF[(long)r * 300 + c] = v;
                        csum[nj] += v; csq[nj] += v * v;
                    }
                }
        #pragma unroll
        for (int nj = 0; nj < 5; ++nj) {
            const int cl = wn * 80 + nj * 16 + rl;
            if (cl < 300) {
                atomicAdd(&sSum[cl], csum[nj]);
                atomicAdd(&sSq[cl], csq[nj]);
            }
        }
        __syncthreads();
        const int slot = blockIdx.x & (NPART - 1);
        for (int i = tid; i < 300; i += 256) {
            atomicAdd(&part[slot * 600 + i], sSum[i]);
            atomicAdd(&part[slot * 600 + 300 + i], sSq[i]);
        }
    }
}

// ---------- edge pass: block owns SEGB contiguous segments; plain float stores ----------
__launch_bounds__(320)
__global__ void edge_pass(const bf16_t* __restrict__ Gb,   // [N_last][320]
                          const float* __restrict__ last_coors,
                          const float* __restrict__ cur_coors,
                          const int2* __restrict__ sorted,  // (li, ci), sorted by ci
                          const int*  __restrict__ segEnd,  // end offsets per cur node
                          const float* __restrict__ Wc,     // rows 300..302 of W1, 3x300
                          const float* __restrict__ g1,
                          float* __restrict__ zbuf,         // [N_cur][320] raw max (m)
                          float* __restrict__ part1,
                          int N_cur)
{
    __shared__ int sRow[2][CHS], sCi[2][CHS];
    __shared__ float sD0[2][CHS], sD1[2][CHS], sD2[2][CHS];

    const int tid = threadIdx.x;
    const int st  = (tid >= 160) ? 1 : 0;
    const int ts  = tid - st * 160;          // 0..159 within stream

    const int g0   = blockIdx.x * SEGB;
    const int gEnd = min(g0 + SEGB, N_cur);
    const int gMid = min(g0 + SEGB / 2, gEnd);

    const int e00 = (g0   == 0) ? 0 : segEnd[g0 - 1];
    const int e01 = (gMid == 0) ? 0 : segEnd[gMid - 1];
    const int e11 = (gEnd == 0) ? 0 : segEnd[gEnd - 1];

    const int ebeg = st ? e01 : e00;
    const int eend = st ? e11 : e01;

    const int nch0 = (e01 - e00 + CHS - 1) / CHS;
    const int nch1 = (e11 - e01 + CHS - 1) / CHS;
    const int nch  = max(nch0, nch1);

    const int ft = ts * 2;                   // feature pair {ft, ft+1}, ft<=318
    const bool real = (ft < 300);
    float w00 = 0.f, w01 = 0.f, w10 = 0.f, w11 = 0.f, w20 = 0.f, w21 = 0.f;
    float sgn0 = 1.f, sgn1 = 1.f;
    if (real) {
        w00 = Wc[ft];        w01 = Wc[ft + 1];
        w10 = Wc[300 + ft];  w11 = Wc[300 + ft + 1];
        w20 = Wc[600 + ft];  w21 = Wc[600 + ft + 1];
        sgn0 = (g1[ft]     < 0.f) ? -1.f : 1.f;
        sgn1 = (g1[ft + 1] < 0.f) ? -1.f : 1.f;
    }

    int cur = -1;                            // -1 = no open segment
    float m0 = -3.4e38f, m1 = -3.4e38f;
    float sum0 = 0.f, sq0 = 0.f, sum1 = 0.f, sq1 = 0.f;

    for (int ch = 0; ch < nch; ++ch) {
        const int cbeg = ebeg + ch * CHS;
        const int ccnt = min(CHS, eend - cbeg);   // may be <= 0

        for (int i = ts; i < ccnt; i += 160) {
            const int2 r = sorted[cbeg + i];
            sRow[st][i] = r.x * 320;
            sCi[st][i]  = r.y;
            sD0[st][i] = last_coors[r.x * 3 + 0] - cur_coors[r.y * 3 + 0];
            sD1[st][i] = last_coors[r.x * 3 + 1] - cur_coors[r.y * 3 + 1];
            sD2[st][i] = last_coors[r.x * 3 + 2] - cur_coors[r.y * 3 + 2];
        }
        __syncthreads();

        int i = 0;
        for (; i + UNR <= ccnt; i += UNR) {
            unsigned gu[UNR];
            #pragma unroll
            for (int j = 0; j < UNR; ++j)
                gu[j] = *reinterpret_cast<const unsigned*>(&Gb[(long)sRow[st][i + j] + ft]);
            #pragma unroll
            for (int j = 0; j < UNR; ++j) {
                const int ci = sCi[st][i + j];
                if (ci != cur) {               // stream-uniform branch
                    if (cur >= 0)
                        *reinterpret_cast<float2*>(&zbuf[(long)cur * 320 + ft]) =
                            make_float2(m0, m1);
                    cur = ci;
                    m0 = -3.4e38f; m1 = -3.4e38f;
                }
                const float gx = __uint_as_float(gu[j] << 16);
                const float gy = __uint_as_float(gu[j] & 0xffff0000u);
                const float d0 = sD0[st][i + j], d1 = sD1[st][i + j], d2 = sD2[st][i + j];
                const float y0 = fmaxf(gx + d0 * w00 + d1 * w10 + d2 * w20, 0.f);
                const float y1 = fmaxf(gy + d0 * w01 + d1 * w11 + d2 * w21, 0.f);
                sum0 += y0; sq0 += y0 * y0; m0 = fmaxf(m0, sgn0 * y0);
                sum1 += y1; sq1 += y1 * y1; m1 = fmaxf(m1, sgn1 * y1);
            }
        }
        for (; i < ccnt; ++i) {
            const int ci = sCi[st][i];
            if (ci != cur) {
                if (cur >= 0)
                    *reinterpret_cast<float2*>(&zbuf[(long)cur * 320 + ft]) =
                        make_float2(m0, m1);
                cur = ci;
                m0 = -3.4e38f; m1 = -3.4e38f;
            }
            const unsigned gu = *reinterpret_cast<const unsigned*>(&Gb[(long)sRow[st][i] + ft]);
            const float gx = __uint_as_float(gu << 16);
            const float gy = __uint_as_float(gu & 0xffff0000u);
            const float d0 = sD0[st][i], d1 = sD1[st][i], d2 = sD2[st][i];
            const float y0 = fmaxf(gx + d0 * w00 + d1 * w10 + d2 * w20, 0.f);
            const float y1 = fmaxf(gy + d0 * w01 + d1 * w11 + d2 * w21, 0.f);
            sum0 += y0; sq0 += y0 * y0; m0 = fmaxf(m0, sgn0 * y0);
            sum1 += y1; sq1 += y1 * y1; m1 = fmaxf(m1, sgn1 * y1);
        }
        __syncthreads();   // protect LDS before next chunk's staging
    }
    if (cur >= 0)
        *reinterpret_cast<float2*>(&zbuf[(long)cur * 320 + ft]) = make_float2(m0, m1);

    const int slot = blockIdx.x & (NPART - 1);
    if (real) {
        atomicAdd(&part1[slot * 600 + ft],           sum0);
        atomicAdd(&part1[slot * 600 + ft + 1],       sum1);
        atomicAdd(&part1[slot * 600 + 300 + ft],     sq0);
        atomicAdd(&part1[slot * 600 + 300 + ft + 1], sq1);
    }
}

// ---------- reduce partials -> per-feature affine; ac layout a:[0..319] c:[320..639] ----------
__global__ void stats_finalize(const float* __restrict__ part,
                               const float* __restrict__ g,
                               const float* __restrict__ be,
                               float invCnt, float* __restrict__ ac)
{
    const int t = threadIdx.x;   // 320 threads
    if (t >= 300) {
        if (t < 320) { ac[t] = 0.f; ac[320 + t] = 0.f; }   // zero pads
        return;
    }
    float sum = 0.f, sq = 0.f;
    for (int p = 0; p < NPART; ++p) {
        sum += part[p * 600 + t];
        sq  += part[p * 600 + 300 + t];
    }
    const float mean = sum * invCnt;
    const float var = fmaxf(sq * invCnt - mean * mean, 0.f);
    const float inv = rsqrtf(var + 1e-5f);
    const float a = g[t] * inv;
    ac[t] = a;
    ac[320 + t] = be[t] - mean * a;
}

// ---------- apply BN2 affine to d_out in place ----------
__global__ void finalize_out(float* __restrict__ out,
                             const float* __restrict__ ac2)
{
    const int t = threadIdx.x;
    if (t >= 300) return;
    const long i = (long)blockIdx.x * 300 + t;
    out[i] = ac2[t] * out[i] + ac2[320 + t];
}

extern "C" void kernel_launch(void* const* d_in, const int* in_sizes, int n_in,
                              void* d_out, int out_size, void* d_ws, size_t ws_size,
                              hipStream_t stream)
{
    const float* last_coors    = (const float*)d_in[0];
    const float* last_features = (const float*)d_in[1];
    const float* cur_coors     = (const float*)d_in[2];
    const int*   cur_idx       = (const int*)d_in[3];
    const int*   last_idx      = (const int*)d_in[4];
    const float* W1  = (const float*)d_in[5];
    const float* b1  = (const float*)d_in[6];
    const float* g1  = (const float*)d_in[7];
    const float* be1 = (const float*)d_in[8];
    const float* W2  = (const float*)d_in[9];
    const float* b2  = (const float*)d_in[10];
    const float* g2  = (const float*)d_in[11];
    const float* be2 = (const float*)d_in[12];
    float* out = (float*)d_out;

    const int N_last = in_sizes[0] / 3;
    const int N_cur  = in_sizes[2] / 3;
    const int E      = in_sizes[3];

    const int nb1 = (N_cur + SB - 1) / SB;

    // ---- workspace ----
    char* ws = (char*)d_ws;
    size_t off = 0;
    bf16_t* Gb = (bf16_t*)(ws + off);  off += (size_t)N_last * 320 * 2;
    off = (off + 255) & ~(size_t)255;
    float* zbuf = (float*)(ws + off);  off += (size_t)N_cur * 320 * 4;
    off = (off + 255) & ~(size_t)255;
    int2* sorted = (int2*)(ws + off);  off += (size_t)E * 8;
    int* hist = (int*)(ws + off);      off += (size_t)nb1 * SB * 4;
    int* cnt  = (int*)(ws + off);      off += (size_t)nb1 * SB * 4;
    int* bsum = (int*)(ws + off);      off += 256 * 4;
    bf16_t* WT1 = (bf16_t*)(ws + off); off += (size_t)384 * 320 * 2;
    bf16_t* WT2 = (bf16_t*)(ws + off); off += (size_t)384 * 320 * 2;
    float* part1 = (float*)(ws + off); off += (size_t)NPART * 600 * 4;
    float* part2 = (float*)(ws + off); off += (size_t)NPART * 600 * 4;
    float* ac1   = (float*)(ws + off); off += 640 * 4;
    float* ac2   = (float*)(ws + off); off += 640 * 4;

    hipMemsetAsync(hist, 0, (size_t)nb1 * SB * 4, stream);
    hipMemsetAsync(part1, 0, (size_t)2 * NPART * 600 * 4, stream);  // part1+part2

    // ---- counting sort of edges by cur_idx ----
    hist_k<<<(E + 255) / 256, 256, 0, stream>>>(cur_idx, E, hist);
    scan_reduce<<<nb1, SB, 0, stream>>>(hist, N_cur, bsum);
    scan_top<<<1, SB, 0, stream>>>(bsum, nb1);
    scan_final<<<nb1, SB, 0, stream>>>(hist, N_cur, bsum, cnt);
    scatter_k<<<(E + 255) / 256, 256, 0, stream>>>(cur_idx, last_idx, E, cnt, sorted);
    // cnt is now the per-segment END offset array

    // ---- weights ----
    pack_wt2<<<960, 256, 0, stream>>>(W1, W2, WT1);   // WT1,WT2 contiguous

    // gemm0: G = lf @ W1[:300] + b1 (fp32 A read + cvt fused; writes Gb [M][320])
    gemm_mfma<0><<<(N_last + 63) / 64, 256, 0, stream>>>(
        last_features, N_last, nullptr, nullptr, WT1, b1, Gb, nullptr, nullptr);

    // edge pass: one block per SEGB segments; plain float stores to zbuf
    const int nSB = (N_cur + SEGB - 1) / SEGB;
    edge_pass<<<nSB, 320, 0, stream>>>(Gb, last_coors, cur_coors, sorted, cnt,
                                       W1 + 300 * 300, g1, zbuf, part1, N_cur);

    stats_finalize<<<1, 320, 0, stream>>>(part1, g1, be1, 1.0f / (float)E, ac1);

    // gemm1: A = BN1-affine(zbuf) fused in staging; out_pre = ReLU(A@W2+b2) + stats2
    gemm_mfma<1><<<(N_cur + 63) / 64, 256, 0, stream>>>(
        zbuf, N_cur, cnt, ac1, WT2, b2, nullptr, out, part2);

    stats_finalize<<<1, 320, 0, stream>>>(part2, g2, be2, 1.0f / (float)N_cur, ac2);
    finalize_out<<<N_cur, 320, 0, stream>>>(out, ac2);
}